// Round 10
// baseline (200.932 us; speedup 1.0000x reference)
//
#include <hip/hip_runtime.h>

// Sizes (fixed by the reference)
#define NN 32
#define CC 64
#define TT 300
#define VV 25
#define KK 3
#define OO 64
#define TB 2            // time steps per subtile
#define SB (TB * VV)    // 50 output spatial positions per subtile
#define STRIP 12        // time steps per block
#define NSUB (STRIP/TB) // 6 subtiles per block
#define NSTRIP (TT/STRIP)
#define NREP 64         // replicated stats accumulators
#define XBUF (128 * 32) // one x_s buffer (shorts)

// ws layout (floats):
//  [0..128)         final stats (sum, sumsq per channel)
//  [128..8320)      replica accumulators NREP*128
//  [8320..14464)    Wpk: 1536 short8 W-fragments (24 KB)
//  [14464..16000)   Apk: 384 short8 A-fragments (6 KB)
//  [16384.. )       optional bf16 y buffer (30.72 MB) if ws_size permits
#define REP_OFF 128
#define WPK_OFF 8320
#define APK_OFF 14464
#define YBF_OFF 16384
#define YBF_BYTES ((size_t)NN * OO * TT * VV * 2)
#define WS_NEED_BF16 ((size_t)YBF_OFF * 4 + YBF_BYTES)

typedef __attribute__((ext_vector_type(8))) short short8;  // 8 bf16 = 4 VGPR
typedef __attribute__((ext_vector_type(4))) float f32x4;

// f32 -> bf16, round-to-nearest-even
__device__ __forceinline__ unsigned short f2bf(float f) {
    unsigned u = __builtin_bit_cast(unsigned, f);
    u += 0x7FFFu + ((u >> 16) & 1u);
    return (unsigned short)(u >> 16);
}
__device__ __forceinline__ float bf2f(unsigned short b) {
    return __builtin_bit_cast(float, (unsigned)b << 16);
}
__device__ __forceinline__ int xswz(int row) { return ((row >> 1) & 3) << 3; }

// One-time: zero stats+replicas, pack W and A into exact MFMA fragment layout.
__global__ __launch_bounds__(512) void prep_pack(const float* __restrict__ A,
                                                 const float* __restrict__ W,
                                                 float* __restrict__ ws) {
    const int i = blockIdx.x * 512 + threadIdx.x;  // grid 4 -> 2048 threads
    for (int j = i; j < REP_OFF + NREP * 128; j += 2048) ws[j] = 0.0f;
    unsigned short* Wpk = reinterpret_cast<unsigned short*>(ws + WPK_OFF);
    unsigned short* Apk = reinterpret_cast<unsigned short*>(ws + APK_OFF);
    if (i < 1536) {
        // Wpk[mt][kap][lane]: A-operand frag, row o = mt*16+li, k-elems = kap*32+g*8+e
        int mt = i / 384, r = i - mt * 384;
        int kap = r / 64, lane = r - kap * 64;
        int li = lane & 15, g = lane >> 4;
        int o  = mt * 16 + li;
        int k  = kap >> 1, c0 = (kap & 1) * 32 + g * 8;
        const float* wp = W + ((size_t)(k * OO + o)) * CC + c0;
#pragma unroll
        for (int e = 0; e < 8; ++e) Wpk[i * 8 + e] = f2bf(wp[e]);
    } else if (i < 1920) {
        // Apk[k*2+nt][lane]: B-operand frag (A^T), col w = nt*16+li, k-elems v = g*8+e
        int j = i - 1536;
        int k = j / 128, r = j - k * 128;
        int nt = r / 64, lane = r - nt * 64;
        int li = lane & 15, g = lane >> 4;
        int w = nt * 16 + li;
#pragma unroll
        for (int e = 0; e < 8; ++e) {
            int v = g * 8 + e;
            float val = (v < VV && w < VV) ? A[(k * VV + v) * VV + w] : 0.0f;
            Apk[j * 8 + e] = f2bf(val);
        }
    }
}

// Block: (n, 12-time-step strip), 512 threads = 8 waves, 6 internal subtiles.
// Per-wave fixed cost (~20k cyc: stage latency + barriers + drain) amortized
// over 6 subtiles; x_s double-buffered so subtile j+1's HBM loads hide under
// subtile j's compute (T14 async-stage split).
template <int BF16Y>
__global__ __launch_bounds__(512, 6) void gcn_main(const float* __restrict__ x,
                                                   float* __restrict__ ws,
                                                   float* __restrict__ ypre) {
    __shared__ alignas(16) unsigned short x_s[2 * XBUF];   // 16 KB (double buffer)
    __shared__ alignas(16) unsigned short xa_s[64 * 192];  // 24 KB (rows 50..63 pad,
                                                           // feed masked-out C cols only)
    __shared__ float stats_s[128];

    const int bid  = blockIdx.x;
    const int n    = bid / NSTRIP;
    const int t0   = (bid % NSTRIP) * STRIP;
    const int tid  = threadIdx.x;
    const int lane = tid & 63;
    const int wid  = tid >> 6;
    const int li   = lane & 15;   // fragment row/col index
    const int g    = lane >> 4;   // 16-lane group: k-elems = 8g..8g+7

    const short8* Wpk = reinterpret_cast<const short8*>(ws + WPK_OFF);
    const short8* Apk = reinterpret_cast<const short8*>(ws + APK_OFF);
    unsigned short* ybf = reinterpret_cast<unsigned short*>(ws + YBF_OFF);

    if (tid < 128) stats_s[tid] = 0.0f;

    const float* xg = x + (size_t)n * (CC * TT * VV);

    // ---- prologue: zero K-pad (v=25..31) of BOTH x_s buffers (stage never touches it)
    for (int idx = tid; idx < 2 * 128 * 7; idx += 512) {
        int b = idx / (128 * 7), rr = idx - b * (128 * 7);
        int row = rr / 7, v = 25 + (rr - row * 7);
        x_s[b * XBUF + row * 32 + (v ^ xswz(row))] = 0;
    }
    // stage subtile 0 into buffer 0 (load->reg->LDS; same-wave, no barrier needed yet)
    {
        float2 r[4];
#pragma unroll
        for (int m = 0; m < 4; ++m) {
            int idx = tid + m * 512;
            if (idx < 1600) {
                int c = idx / 25, q = idx - c * 25;
                r[m] = *reinterpret_cast<const float2*>(
                    xg + (size_t)c * (TT * VV) + (size_t)t0 * VV + q * 2);
            }
        }
#pragma unroll
        for (int m = 0; m < 4; ++m) {
            int idx = tid + m * 512;
            if (idx < 1600) {
                int c = idx / 25, q = idx - c * 25;
                float vals[2] = {r[m].x, r[m].y};
#pragma unroll
                for (int i = 0; i < 2; ++i) {
                    int sp = q * 2 + i;
                    int t = sp >= 25 ? 1 : 0, v = sp - t * 25;
                    int row = t * 64 + c;
                    x_s[row * 32 + (v ^ xswz(row))] = f2bf(vals[i]);
                }
            }
        }
    }
    // A^T B-fragments: 6 coalesced 16B loads (pre-packed), hoisted across subtiles
    short8 afrag[6];
#pragma unroll
    for (int kn = 0; kn < 6; ++kn)
        afrag[kn] = *reinterpret_cast<const short8*>(
            reinterpret_cast<const unsigned short*>(Apk) + ((size_t)kn * 64 + lane) * 8);

    float s1a[2][4] = {{0,0,0,0},{0,0,0,0}};
    float s2a[2][4] = {{0,0,0,0},{0,0,0,0}};

    __syncthreads();

    // ---- subtile loop: 2 barriers per iter, stage(j+1) hidden under compute(j)
#pragma unroll 1
    for (int j = 0; j < NSUB; ++j) {
        unsigned short* xsc = x_s + (j & 1) * XBUF;
        unsigned short* xsn = x_s + ((j + 1) & 1) * XBUF;
        const int ts = t0 + j * TB;
        const bool have = (j + 1) < NSUB;

        // issue next subtile's global loads EARLY (latency hides under B+C)
        float2 r[4];
        if (have) {
#pragma unroll
            for (int m = 0; m < 4; ++m) {
                int idx = tid + m * 512;
                if (idx < 1600) {
                    int c = idx / 25, q = idx - c * 25;
                    r[m] = *reinterpret_cast<const float2*>(
                        xg + (size_t)c * (TT * VV) + (size_t)(ts + TB) * VV + q * 2);
                }
            }
        }

        // Phase B: GEMM1. M=(t*64+c) 128 rows = 8 Mtiles (1/wave), N=w (2), K=32
        {
            const int row = wid * 16 + li;
            const short8 xf = *reinterpret_cast<const short8*>(
                &xsc[row * 32 + ((g * 8) ^ xswz(row))]);
            const int r0 = wid * 16 + g * 4;
            const int t = r0 >> 6, c0 = r0 & 63;
#pragma unroll
            for (int k = 0; k < KK; ++k) {
                f32x4 a0 = {0.f,0.f,0.f,0.f}, a1 = {0.f,0.f,0.f,0.f};
                a0 = __builtin_amdgcn_mfma_f32_16x16x32_bf16(xf, afrag[k*2+0], a0, 0, 0, 0);
                a1 = __builtin_amdgcn_mfma_f32_16x16x32_bf16(xf, afrag[k*2+1], a1, 0, 0, 0);
                int kc = k * 64 + c0;
                {
                    int s = t * 25 + li;
                    unsigned long long p =
                        (unsigned long long)f2bf(a0[0]) |
                        ((unsigned long long)f2bf(a0[1]) << 16) |
                        ((unsigned long long)f2bf(a0[2]) << 32) |
                        ((unsigned long long)f2bf(a0[3]) << 48);
                    *reinterpret_cast<unsigned long long*>(
                        &xa_s[s * 192 + (kc ^ ((s & 7) << 3))]) = p;
                }
                int w1 = 16 + li;
                if (w1 < VV) {
                    int s = t * 25 + w1;
                    unsigned long long p =
                        (unsigned long long)f2bf(a1[0]) |
                        ((unsigned long long)f2bf(a1[1]) << 16) |
                        ((unsigned long long)f2bf(a1[2]) << 32) |
                        ((unsigned long long)f2bf(a1[3]) << 48);
                    *reinterpret_cast<unsigned long long*>(
                        &xa_s[s * 192 + (kc ^ ((s & 7) << 3))]) = p;
                }
            }
        }

        // stage-write j+1 -> other buffer (safe: last read 2 barriers ago)
        if (have) {
#pragma unroll
            for (int m = 0; m < 4; ++m) {
                int idx = tid + m * 512;
                if (idx < 1600) {
                    int c = idx / 25, q = idx - c * 25;
                    float vals[2] = {r[m].x, r[m].y};
#pragma unroll
                    for (int i = 0; i < 2; ++i) {
                        int sp = q * 2 + i;
                        int t = sp >= 25 ? 1 : 0, v = sp - t * 25;
                        int row = t * 64 + c;
                        xsn[row * 32 + (v ^ xswz(row))] = f2bf(vals[i]);
                    }
                }
            }
        }
        __syncthreads();  // xa_s ready; x_s[next] staged

        // Phase C: GEMM2. M=o (4 Mtiles), N=s (4 Ntiles), K=192 (6 MFMA), fused stats
#pragma unroll
        for (int i = 0; i < 2; ++i) {
            const int u = wid + 8 * i;       // 0..15 = (mt 0..3, nt 0..3)
            const int mt = u >> 2, nt = u & 3;
            const int srow = nt * 16 + li;
            const short8* wb = Wpk + (size_t)(mt * 6) * 64 + lane;
            f32x4 y = {0.f,0.f,0.f,0.f};
#pragma unroll
            for (int kap = 0; kap < 6; ++kap) {
                const short8 wf  = wb[(size_t)kap * 64];
                const short8 xaf = *reinterpret_cast<const short8*>(
                    &xa_s[srow * 192 + ((kap * 32 + g * 8) ^ ((srow & 7) << 3))]);
                y = __builtin_amdgcn_mfma_f32_16x16x32_bf16(wf, xaf, y, 0, 0, 0);
            }
            const bool sv = srow < SB;
            const int oq = mt * 16 + g * 4;
            const size_t base = ((size_t)n * OO + oq) * (TT * VV) + (size_t)ts * VV + srow;
#pragma unroll
            for (int jj = 0; jj < 4; ++jj) {
                float v = sv ? y[jj] : 0.0f;
                if (BF16Y) {
                    unsigned short b = f2bf(v);
                    float vq = bf2f(b);       // stats on quantized values (consistent BN)
                    if (sv) ybf[base + (size_t)jj * (TT * VV)] = b;
                    s1a[i][jj] += vq;
                    s2a[i][jj] += vq * vq;
                } else {
                    if (sv) ypre[base + (size_t)jj * (TT * VV)] = v;
                    s1a[i][jj] += v;
                    s2a[i][jj] += v * v;
                }
            }
        }
        __syncthreads();  // xa_s consumed before B(j+1) overwrites
    }

    // ---- once per block: shfl-reduce stat accumulators -> LDS -> replicated global
#pragma unroll
    for (int i = 0; i < 2; ++i) {
        const int u = wid + 8 * i;
        const int mt = u >> 2;
        const int oq = mt * 16 + g * 4;
#pragma unroll
        for (int d = 1; d < 16; d <<= 1) {
#pragma unroll
            for (int jj = 0; jj < 4; ++jj) {
                s1a[i][jj] += __shfl_xor(s1a[i][jj], d);
                s2a[i][jj] += __shfl_xor(s2a[i][jj], d);
            }
        }
        if (li == 0) {
#pragma unroll
            for (int jj = 0; jj < 4; ++jj) {
                atomicAdd(&stats_s[oq + jj], s1a[i][jj]);
                atomicAdd(&stats_s[64 + oq + jj], s2a[i][jj]);
            }
        }
    }
    // NOTE: per-branch bias b.sum(0) is a per-channel constant -> exactly
    // cancelled by training-mode BN. Skipped on purpose (exact).
    __syncthreads();
    if (tid < 128)
        atomicAdd(&ws[REP_OFF + (bid & (NREP - 1)) * 128 + tid], stats_s[tid]);
}

// Fold NREP replicas -> final stats at ws[0..128)
__global__ __launch_bounds__(128) void reduce_stats(float* ws) {
    const int t = threadIdx.x;
    float s = 0.0f;
#pragma unroll 8
    for (int r = 0; r < NREP; ++r) s += ws[REP_OFF + r * 128 + t];
    ws[t] = s;
}

__global__ __launch_bounds__(256) void bn_relu_f32(float* __restrict__ y,
                                                   const float* __restrict__ stats,
                                                   const float* __restrict__ gamma,
                                                   const float* __restrict__ beta) {
    const int i4 = blockIdx.x * 256 + threadIdx.x;
    const size_t i = (size_t)i4 * 4;
    const int o = (int)((i / (TT * VV)) % OO);  // TT*VV=7500 divisible by 4

    const float cnt  = (float)NN * TT * VV;
    const float mean = stats[o] / cnt;
    const float var  = stats[OO + o] / cnt - mean * mean;
    const float inv  = rsqrtf(var + 1e-5f);
    const float sc   = gamma[o] * inv;
    const float sh   = beta[o] - mean * sc;

    float4 v = *reinterpret_cast<float4*>(y + i);
    v.x = fmaxf(v.x * sc + sh, 0.0f);
    v.y = fmaxf(v.y * sc + sh, 0.0f);
    v.z = fmaxf(v.z * sc + sh, 0.0f);
    v.w = fmaxf(v.w * sc + sh, 0.0f);
    *reinterpret_cast<float4*>(y + i) = v;
}

__global__ __launch_bounds__(256) void bn_relu_bf(float* __restrict__ out,
                                                  const float* __restrict__ ws,
                                                  const float* __restrict__ gamma,
                                                  const float* __restrict__ beta) {
    const int i4 = blockIdx.x * 256 + threadIdx.x;
    const size_t i = (size_t)i4 * 4;
    const int o = (int)((i / (TT * VV)) % OO);

    const float cnt  = (float)NN * TT * VV;
    const float mean = ws[o] / cnt;
    const float var  = ws[OO + o] / cnt - mean * mean;
    const float inv  = rsqrtf(var + 1e-5f);
    const float sc   = gamma[o] * inv;
    const float sh   = beta[o] - mean * sc;

    const ushort4 u = *reinterpret_cast<const ushort4*>(
        reinterpret_cast<const unsigned short*>(ws + YBF_OFF) + i);
    float4 v;
    v.x = fmaxf(bf2f(u.x) * sc + sh, 0.0f);
    v.y = fmaxf(bf2f(u.y) * sc + sh, 0.0f);
    v.z = fmaxf(bf2f(u.z) * sc + sh, 0.0f);
    v.w = fmaxf(bf2f(u.w) * sc + sh, 0.0f);
    *reinterpret_cast<float4*>(out + i) = v;
}

extern "C" void kernel_launch(void* const* d_in, const int* in_sizes, int n_in,
                              void* d_out, int out_size, void* d_ws, size_t ws_size,
                              hipStream_t stream) {
    const float* x     = (const float*)d_in[0];
    const float* A     = (const float*)d_in[1];
    const float* W     = (const float*)d_in[2];
    // d_in[3] = b : exactly cancelled by training-mode BN, unused
    const float* gamma = (const float*)d_in[4];
    const float* beta  = (const float*)d_in[5];
    float* out = (float*)d_out;
    float* ws  = (float*)d_ws;

    const bool bf16y = ws_size >= WS_NEED_BF16;  // host-side, deterministic

    hipLaunchKernelGGL(prep_pack, dim3(4), dim3(512), 0, stream, A, W, ws);
    if (bf16y) {
        hipLaunchKernelGGL(HIP_KERNEL_NAME(gcn_main<1>), dim3(NN * NSTRIP), dim3(512),
                           0, stream, x, ws, out);
        hipLaunchKernelGGL(reduce_stats, dim3(1), dim3(128), 0, stream, ws);
        hipLaunchKernelGGL(bn_relu_bf, dim3((NN * OO * TT * VV) / 4 / 256), dim3(256),
                           0, stream, out, ws, gamma, beta);
    } else {
        hipLaunchKernelGGL(HIP_KERNEL_NAME(gcn_main<0>), dim3(NN * NSTRIP), dim3(512),
                           0, stream, x, ws, out);
        hipLaunchKernelGGL(reduce_stats, dim3(1), dim3(128), 0, stream, ws);
        hipLaunchKernelGGL(bn_relu_f32, dim3((NN * OO * TT * VV) / 4 / 256), dim3(256),
                           0, stream, out, ws, gamma, beta);
    }
}

// Round 12
// 73.638 us; speedup vs baseline: 2.7287x; 2.7287x over previous
//
#include <hip/hip_runtime.h>

// Sizes (fixed by the reference)
#define NN 32
#define CC 64
#define TT 300
#define VV 25
#define KK 3
#define OO 64
#define TB 4          // time steps per block
#define SB (TB * VV)  // 100 output spatial positions per block

// ws layout (floats):
//  [0..128)        final stats (sum, sumsq per channel)
//  [128..6272)     Wpk: 1536 short8 W-fragments (24 KB)
//  [6272..7808)    Apk: 384 short8 A-fragments (6 KB)
//  [16384..)       bf16 y buffer (30.72 MB) if ws_size permits
#define WPK_OFF 128
#define APK_OFF (128 + 6144)
#define YBF_OFF 16384
#define YBF_BYTES ((size_t)NN * OO * TT * VV * 2)
#define WS_NEED_BF16 ((size_t)YBF_OFF * 4 + YBF_BYTES)

typedef __attribute__((ext_vector_type(8))) short short8;  // 8 bf16 = 4 VGPR
typedef __attribute__((ext_vector_type(4))) float f32x4;
typedef __attribute__((ext_vector_type(4))) unsigned int u32x4;

// f32 -> bf16, round-to-nearest-even
__device__ __forceinline__ unsigned short f2bf(float f) {
    unsigned u = __builtin_bit_cast(unsigned, f);
    u += 0x7FFFu + ((u >> 16) & 1u);
    return (unsigned short)(u >> 16);
}
__device__ __forceinline__ float bf2f(unsigned short b) {
    return __builtin_bit_cast(float, (unsigned)b << 16);
}
// pack two f32 -> u32 of 2 bf16 (RNE; integer pack, trivially copyable)
__device__ __forceinline__ unsigned pk2(float a, float b) {
    return (unsigned)f2bf(a) | ((unsigned)f2bf(b) << 16);
}
__device__ __forceinline__ int xswz(int row) { return ((row >> 1) & 3) << 3; }

// One-time: zero stats, pack W and A into exact MFMA fragment layout.
__global__ __launch_bounds__(512) void prep_pack(const float* __restrict__ A,
                                                 const float* __restrict__ W,
                                                 float* __restrict__ ws) {
    const int i = blockIdx.x * 512 + threadIdx.x;  // grid 4 -> 2048 threads
    if (i < 128) ws[i] = 0.0f;
    unsigned short* Wpk = reinterpret_cast<unsigned short*>(ws + WPK_OFF);
    unsigned short* Apk = reinterpret_cast<unsigned short*>(ws + APK_OFF);
    if (i < 1536) {
        // Wpk[mt][kap][lane]: A-operand frag, row o = mt*16+li, k-elems = kap*32+g*8+e
        int mt = i / 384, r = i - mt * 384;
        int kap = r / 64, lane = r - kap * 64;
        int li = lane & 15, g = lane >> 4;
        int o  = mt * 16 + li;
        int k  = kap >> 1, c0 = (kap & 1) * 32 + g * 8;
        const float* wp = W + ((size_t)(k * OO + o)) * CC + c0;
#pragma unroll
        for (int e = 0; e < 8; ++e) Wpk[i * 8 + e] = f2bf(wp[e]);
    } else if (i < 1920) {
        // Apk[k*2+nt][lane]: B-operand frag (A^T), col w = nt*16+li, k-elems v = g*8+e
        int j = i - 1536;
        int k = j / 128, r = j - k * 128;
        int nt = r / 64, lane = r - nt * 64;
        int li = lane & 15, g = lane >> 4;
        int w = nt * 16 + li;
#pragma unroll
        for (int e = 0; e < 8; ++e) {
            int v = g * 8 + e;
            float val = (v < VV && w < VV) ? A[(k * VV + v) * VV + w] : 0.0f;
            Apk[j * 8 + e] = f2bf(val);
        }
    }
}

// Block: (n, 4 time steps), 512 threads = 8 waves. R6's proven 2-barrier schedule.
//  Phase A: stage x -> bf16 x_s (+ stage Wpk -> LDS, overlapped)
//  Phase B: GEMM1 all k -> xa_s[s=t*25+w][kc=k*64+c]  (packed uint2 epilogue)
//  Phase C: GEMM2 K=192 from LDS Wpk -> stores (bf16 or f32). NO in-kernel stats
//  (register state never spans barriers -> no spill; R7/R10 lesson).
template <int BF16Y>
__global__ __launch_bounds__(512, 4) void gcn_main(const float* __restrict__ x,
                                                   float* __restrict__ ws,
                                                   float* __restrict__ ypre) {
    __shared__ alignas(16) unsigned short x_s[256 * 32];    // 16.0 KB
    __shared__ alignas(16) unsigned short xa_s[100 * 192];  // 38.4 KB (no pad rows:
                                                            // invalid srow reads clamped)
    __shared__ alignas(16) unsigned short wpk_s[1536 * 8];  // 24.0 KB
    // total 79360 B -> 2 blocks/CU

    const int bid  = blockIdx.x;
    const int n    = bid / (TT / TB);
    const int t0   = (bid % (TT / TB)) * TB;
    const int tid  = threadIdx.x;
    const int lane = tid & 63;
    const int wid  = tid >> 6;
    const int li   = lane & 15;   // fragment row/col index
    const int g    = lane >> 4;   // 16-lane group: k-elems = 8g..8g+7

    // ---- Phase A0: stage Wpk -> LDS (3 x 16B per thread; latency hides under A)
    {
        const u32x4* Wg = reinterpret_cast<const u32x4*>(ws + WPK_OFF);
        u32x4* Wl = reinterpret_cast<u32x4*>(wpk_s);
#pragma unroll
        for (int m = 0; m < 3; ++m) Wl[tid + m * 512] = Wg[tid + m * 512];
    }

    // ---- Phase A: stage x (coalesced float4 global, scalar bf16 LDS writes)
    const float* xg = x + (size_t)n * (CC * TT * VV) + (size_t)t0 * VV;
    for (int idx = tid; idx < CC * 25; idx += 512) {  // 1600 float4
        int c = idx / 25, q = idx - c * 25;
        const float4 f = *reinterpret_cast<const float4*>(xg + (size_t)c * (TT * VV) + q * 4);
        float vals[4] = {f.x, f.y, f.z, f.w};
        int s0 = q * 4;
#pragma unroll
        for (int i = 0; i < 4; ++i) {
            int sp = s0 + i;               // may straddle the 25-joint boundary
            int t = sp / 25, v = sp - t * 25;
            int row = t * 64 + c;
            x_s[row * 32 + (v ^ xswz(row))] = f2bf(vals[i]);
        }
    }
    for (int idx = tid; idx < 256 * 7; idx += 512) {  // zero-fill K-pad v=25..31
        int row = idx / 7, v = 25 + (idx - row * 7);
        x_s[row * 32 + (v ^ xswz(row))] = 0;
    }

    // ---- A^T B-fragments: 6 coalesced 16B loads (pre-packed)
    short8 afrag[6];
#pragma unroll
    for (int kn = 0; kn < 6; ++kn)
        afrag[kn] = *reinterpret_cast<const short8*>(
            reinterpret_cast<const unsigned short*>(ws + APK_OFF) + ((size_t)kn * 64 + lane) * 8);

    __syncthreads();

    // ---- Phase B: GEMM1. M=(t*64+c) 256 rows = 16 Mtiles, N=w (2 tiles), K=32.
    // mt outer / k inner: x-frag read once per mt; k-offset in xa is +128B immediate.
    for (int mt = wid; mt < 16; mt += 8) {
        const int row = mt * 16 + li;
        const short8 xf = *reinterpret_cast<const short8*>(
            &x_s[row * 32 + ((g * 8) ^ xswz(row))]);
        const int r0 = mt * 16 + g * 4;
        const int t = r0 >> 6, c0 = r0 & 63;
        const int s0 = t * 25 + li;
        const int w1 = 16 + li;
        const bool w1v = w1 < VV;
        const int s1 = t * 25 + w1;
        unsigned short* p0 = &xa_s[s0 * 192 + (c0 ^ ((s0 & 7) << 3))];
        unsigned short* p1 = &xa_s[(w1v ? s1 : 0) * 192 + (c0 ^ (((w1v ? s1 : 0) & 7) << 3))];
#pragma unroll
        for (int k = 0; k < KK; ++k) {
            f32x4 a0 = {0.f,0.f,0.f,0.f}, a1 = {0.f,0.f,0.f,0.f};
            a0 = __builtin_amdgcn_mfma_f32_16x16x32_bf16(xf, afrag[k * 2 + 0], a0, 0, 0, 0);
            a1 = __builtin_amdgcn_mfma_f32_16x16x32_bf16(xf, afrag[k * 2 + 1], a1, 0, 0, 0);
            uint2 q0 = make_uint2(pk2(a0[0], a0[1]), pk2(a0[2], a0[3]));
            *reinterpret_cast<uint2*>(p0 + k * 64) = q0;
            if (w1v) {
                uint2 q1 = make_uint2(pk2(a1[0], a1[1]), pk2(a1[2], a1[3]));
                *reinterpret_cast<uint2*>(p1 + k * 64) = q1;
            }
        }
    }
    __syncthreads();

    // ---- Phase C: GEMM2. M=o (4 Mtiles), N=s (7 Ntiles, last ragged), K=192 (6 MFMA).
    // W fragments from LDS (staged once; was 168 KB/block of L2 re-reads on the
    // critical path). Invalid srow lanes clamp the xa read to row 0 (their MFMA
    // output columns are exactly the masked-out ones).
    unsigned short* ybf = reinterpret_cast<unsigned short*>(ws + YBF_OFF);
    const int ttv = TT * VV;
    for (int u = wid; u < 28; u += 8) {
        const int mt = u / 7, nt = u - mt * 7;
        const int srow = nt * 16 + li;
        const bool sv = srow < SB;
        const int sr = sv ? srow : 0;
        const short8* wb = reinterpret_cast<const short8*>(wpk_s) + (size_t)(mt * 6) * 64 + lane;
        const unsigned short* xb = &xa_s[sr * 192];
        const int sw = (sr & 7) << 3;
        f32x4 y = {0.f,0.f,0.f,0.f};
#pragma unroll
        for (int kap = 0; kap < 6; ++kap) {
            const short8 wf  = wb[(size_t)kap * 64];
            const short8 xaf = *reinterpret_cast<const short8*>(xb + ((kap * 32 + g * 8) ^ sw));
            y = __builtin_amdgcn_mfma_f32_16x16x32_bf16(wf, xaf, y, 0, 0, 0);
        }
        const int oq = mt * 16 + g * 4;
        const size_t base = ((size_t)n * OO + oq) * ttv + (size_t)t0 * VV + srow;
        if (BF16Y) {
            unsigned p01 = pk2(y[0], y[1]);
            unsigned p23 = pk2(y[2], y[3]);
            if (sv) {
                ybf[base          ] = (unsigned short)p01;
                ybf[base +     ttv] = (unsigned short)(p01 >> 16);
                ybf[base + 2 * ttv] = (unsigned short)p23;
                ybf[base + 3 * ttv] = (unsigned short)(p23 >> 16);
            }
        } else {
            if (sv) {
                ypre[base          ] = y[0];
                ypre[base +     ttv] = y[1];
                ypre[base + 2 * ttv] = y[2];
                ypre[base + 3 * ttv] = y[3];
            }
        }
    }
    // NOTE: per-branch bias b.sum(0) is a per-channel constant -> exactly
    // cancelled by training-mode BN. Skipped on purpose (exact).
}

// Per-channel sum/sumsq over y (bandwidth-bound; bf16 variant reads 31 MB).
template <int BF16Y>
__global__ __launch_bounds__(256) void stats_pass(const void* __restrict__ src,
                                                  float* __restrict__ ws) {
    __shared__ float red[8];
    const int b = blockIdx.x;   // n*64 + o
    const int o = b & 63;
    float s1 = 0.0f, s2 = 0.0f;
    if (BF16Y) {
        const ushort4* p = reinterpret_cast<const ushort4*>(
            reinterpret_cast<const unsigned short*>(src) + (size_t)b * (TT * VV));
        for (int i = threadIdx.x; i < (TT * VV) / 4; i += 256) {
            ushort4 u = p[i];
            float a = bf2f(u.x), c = bf2f(u.y), d = bf2f(u.z), e = bf2f(u.w);
            s1 += a + c + d + e;
            s2 += a * a + c * c + d * d + e * e;
        }
    } else {
        const float4* p = reinterpret_cast<const float4*>(
            reinterpret_cast<const float*>(src) + (size_t)b * (TT * VV));
        for (int i = threadIdx.x; i < (TT * VV) / 4; i += 256) {
            float4 v = p[i];
            s1 += v.x + v.y + v.z + v.w;
            s2 += v.x * v.x + v.y * v.y + v.z * v.z + v.w * v.w;
        }
    }
#pragma unroll
    for (int d = 1; d < 64; d <<= 1) {
        s1 += __shfl_xor(s1, d);
        s2 += __shfl_xor(s2, d);
    }
    const int w = threadIdx.x >> 6;
    if ((threadIdx.x & 63) == 0) { red[w] = s1; red[4 + w] = s2; }
    __syncthreads();
    if (threadIdx.x == 0) {
        atomicAdd(&ws[o],      red[0] + red[1] + red[2] + red[3]);
        atomicAdd(&ws[64 + o], red[4] + red[5] + red[6] + red[7]);
    }
}

__global__ __launch_bounds__(256) void bn_relu_f32(float* __restrict__ y,
                                                   const float* __restrict__ stats,
                                                   const float* __restrict__ gamma,
                                                   const float* __restrict__ beta) {
    const int i4 = blockIdx.x * 256 + threadIdx.x;
    const size_t i = (size_t)i4 * 4;
    const int o = (int)((i / (TT * VV)) % OO);  // TT*VV=7500 divisible by 4

    const float cnt  = (float)NN * TT * VV;
    const float mean = stats[o] / cnt;
    const float var  = stats[OO + o] / cnt - mean * mean;
    const float inv  = rsqrtf(var + 1e-5f);
    const float sc   = gamma[o] * inv;
    const float sh   = beta[o] - mean * sc;

    float4 v = *reinterpret_cast<float4*>(y + i);
    v.x = fmaxf(v.x * sc + sh, 0.0f);
    v.y = fmaxf(v.y * sc + sh, 0.0f);
    v.z = fmaxf(v.z * sc + sh, 0.0f);
    v.w = fmaxf(v.w * sc + sh, 0.0f);
    *reinterpret_cast<float4*>(y + i) = v;
}

__global__ __launch_bounds__(256) void bn_relu_bf(float* __restrict__ out,
                                                  const float* __restrict__ ws,
                                                  const float* __restrict__ gamma,
                                                  const float* __restrict__ beta) {
    const int i4 = blockIdx.x * 256 + threadIdx.x;
    const size_t i = (size_t)i4 * 4;
    const int o = (int)((i / (TT * VV)) % OO);

    const float cnt  = (float)NN * TT * VV;
    const float mean = ws[o] / cnt;
    const float var  = ws[OO + o] / cnt - mean * mean;
    const float inv  = rsqrtf(var + 1e-5f);
    const float sc   = gamma[o] * inv;
    const float sh   = beta[o] - mean * sc;

    const ushort4 u = *reinterpret_cast<const ushort4*>(
        reinterpret_cast<const unsigned short*>(ws + YBF_OFF) + i);
    float4 v;
    v.x = fmaxf(bf2f(u.x) * sc + sh, 0.0f);
    v.y = fmaxf(bf2f(u.y) * sc + sh, 0.0f);
    v.z = fmaxf(bf2f(u.z) * sc + sh, 0.0f);
    v.w = fmaxf(bf2f(u.w) * sc + sh, 0.0f);
    *reinterpret_cast<float4*>(out + i) = v;
}

extern "C" void kernel_launch(void* const* d_in, const int* in_sizes, int n_in,
                              void* d_out, int out_size, void* d_ws, size_t ws_size,
                              hipStream_t stream) {
    const float* x     = (const float*)d_in[0];
    const float* A     = (const float*)d_in[1];
    const float* W     = (const float*)d_in[2];
    // d_in[3] = b : exactly cancelled by training-mode BN, unused
    const float* gamma = (const float*)d_in[4];
    const float* beta  = (const float*)d_in[5];
    float* out = (float*)d_out;
    float* ws  = (float*)d_ws;

    const bool bf16y = ws_size >= WS_NEED_BF16;  // host-side, deterministic

    hipLaunchKernelGGL(prep_pack, dim3(4), dim3(512), 0, stream, A, W, ws);
    if (bf16y) {
        hipLaunchKernelGGL(HIP_KERNEL_NAME(gcn_main<1>), dim3(NN * (TT / TB)), dim3(512),
                           0, stream, x, ws, out);
        hipLaunchKernelGGL(HIP_KERNEL_NAME(stats_pass<1>), dim3(NN * OO), dim3(256),
                           0, stream, (const void*)(ws + YBF_OFF), ws);
        hipLaunchKernelGGL(bn_relu_bf, dim3((NN * OO * TT * VV) / 4 / 256), dim3(256),
                           0, stream, out, ws, gamma, beta);
    } else {
        hipLaunchKernelGGL(HIP_KERNEL_NAME(gcn_main<0>), dim3(NN * (TT / TB)), dim3(512),
                           0, stream, x, ws, out);
        hipLaunchKernelGGL(HIP_KERNEL_NAME(stats_pass<0>), dim3(NN * OO), dim3(256),
                           0, stream, (const void*)out, ws);
        hipLaunchKernelGGL(bn_relu_f32, dim3((NN * OO * TT * VV) / 4 / 256), dim3(256),
                           0, stream, out, ws, gamma, beta);
    }
}